// Round 13
// baseline (76.683 us; speedup 1.0000x reference)
//
#include <hip/hip_runtime.h>
#include <hip/hip_bf16.h>

#define NN    4096
#define KNEI  16
#define QPW   4              // query nodes per wave
#define WPB   16             // waves per block
#define BLOCK (WPB * 64)
#define QPB   (WPB * QPW)    // 64 queries per block
#define NEGB  -3.0e38f
#define PACKM 0xFFFFFFC0

typedef float f32x2 __attribute__((ext_vector_type(2)));

__device__ __forceinline__ int rlane(int v, int l)
{ return __builtin_amdgcn_readlane(v, l); }
__device__ __forceinline__ float rlanef(float v, int l)
{ return __int_as_float(__builtin_amdgcn_readlane(__float_as_int(v), l)); }

// -n2/2 recomputed identically at every use site (phase1, replay)
__device__ __forceinline__ float neg_half_n2(float x, float y, float z)
{
    return fmaf(-0.5f * x, x, fmaf(-0.5f * y, y, __fmul_rn(-0.5f * z, z)));
}

// ---- DPP argmax step: (f,i) joint max, index carried via cndmask ----
template<int CTRL>
__device__ __forceinline__ void amax_step(float& f, int& i)
{
    int fs = __builtin_amdgcn_update_dpp(__float_as_int(f), __float_as_int(f),
                                         CTRL, 0xF, 0xF, false);
    int is = __builtin_amdgcn_update_dpp(i, i, CTRL, 0xF, 0xF, false);
    float ff = __int_as_float(fs);
    bool gt = ff > f;
    f = gt ? ff : f;
    i = gt ? is : i;
}

// full-wave argmax (index-carry); (M, mi) broadcast via lane 63
__device__ __forceinline__ void wave_amax(float f, int i, float& M, int& mi)
{
    amax_step<0x111>(f, i); amax_step<0x112>(f, i); amax_step<0x114>(f, i);
    amax_step<0x118>(f, i); amax_step<0x142>(f, i); amax_step<0x143>(f, i);
    M  = rlanef(f, 63);
    mi = rlane(i, 63);
}

// row-16 all-lanes argmax via rotate-reduce (row_ror:1/2/4/8)
__device__ __forceinline__ void row_amax(float& f, int& i)
{
    amax_step<0x121>(f, i); amax_step<0x122>(f, i);
    amax_step<0x124>(f, i); amax_step<0x128>(f, i);
}

__device__ __forceinline__ float row16_sum_dpp(float v)  // lane 16r+15 -> row sum
{
    float f = v;
#define STEPA(CTRL)                                                          \
    { int s_ = __builtin_amdgcn_update_dpp(0, __float_as_int(f),             \
               (CTRL), 0xF, 0xF, true);                                      \
      f += __int_as_float(s_); }
    STEPA(0x111) STEPA(0x112) STEPA(0x114) STEPA(0x118)
#undef STEPA
    return f;
}

__device__ __forceinline__ float bpermf(int abyte, float v)
{ return __int_as_float(__builtin_amdgcn_ds_bpermute(abyte, __float_as_int(v))); }

__device__ __forceinline__ float sel4f(float a, float b, float c, float d, int q)
{
    float lo = (q & 1) ? b : a;
    float hi = (q & 1) ? d : c;
    return (q & 2) ? hi : lo;
}

// packed ladder: index lives in low 6 mantissa bits (c = J>>6)
#define LADDER(dp, b, s)                                          \
    {  (s) = __builtin_amdgcn_fmed3f((dp), (s), (b));             \
       (b) = fmaxf((b), (dp)); }

// purge self (always its column's packed max, possibly packed 2nd)
#define SELFFIX(q, b, s)                                                     \
    {  int cb_ = __float_as_int(b) & 63;                                     \
       if ((((cb_) << 6) | (lane ^ cb_)) == q0 + (q)) { (b) = (s); (s) = NEGB; } \
       int cs_ = __float_as_int(s) & 63;                                     \
       if ((((cs_) << 6) | (lane ^ cs_)) == q0 + (q)) { (s) = NEGB; } }

// rare wave-wide replay for query q: rebuild column colq's top-2 unselected
#define REPLAY(q, xq, yq, zq)                                                \
    {   int colq = rlane(colw, 16 * (q));                                    \
        int kq   = rlane(kw,   16 * (q));                                    \
        int j2 = (lane << 6) | (colq ^ lane);                                \
        float Rx = sx[j2], Ry = sy[j2], Rz = sz[j2];                         \
        float Rw = neg_half_n2(Rx, Ry, Rz);                                  \
        float scr = fmaf(Rx, (xq), fmaf(Ry, (yq), fmaf(Rz, (zq), Rw)));      \
        float sf = __int_as_float((__float_as_int(scr) & PACKM) | lane);     \
        if (j2 == q0 + (q)) sf = NEGB;                                       \
        _Pragma("unroll")                                                    \
        for (int t = 0; t < KNEI; ++t) {                                     \
            int sv = rlane(selIdx, 16 * (q) + t);                            \
            if (j2 == sv) sf = NEGB;                                         \
        }                                                                    \
        float M1; int i1;                                                    \
        wave_amax(sf, j2, M1, i1);                                           \
        float sf2 = (j2 == i1) ? NEGB : sf;                                  \
        float M2; int i2;                                                    \
        wave_amax(sf2, j2, M2, i2);                                          \
        bool ow = (lane == 16 * (q) + (colq & 15));                          \
        if (kq == 0)      { pb0 = ow ? M1 : pb0; ps0 = ow ? M2 : ps0; }      \
        else if (kq == 1) { pb1 = ow ? M1 : pb1; ps1 = ow ? M2 : ps1; }      \
        else if (kq == 2) { pb2 = ow ? M1 : pb2; ps2 = ow ? M2 : ps2; }      \
        else              { pb3 = ow ? M1 : pb3; ps3 = ow ? M2 : ps3; }      \
    }

#define PROMOTE(k, pb, ps)                                                   \
    {   bool pk = own && (kw == (k));                                        \
        exh = exh || (pk && ((ps) == NEGB));                                 \
        (pb) = pk ? (ps)  : (pb);                                            \
        (ps) = pk ? NEGB : (ps);                                             \
    }

__global__ __launch_bounds__(BLOCK, 8)
void protein_enc_kernel(const float* __restrict__ coords,
                        const int*   __restrict__ atypes,
                        const int*   __restrict__ rtypes,
                        const float* __restrict__ tpw,
                        const float* __restrict__ aemb,
                        const float* __restrict__ remb,
                        float* __restrict__ out)
{
    __shared__ float sx[NN];        // 16 KB
    __shared__ float sy[NN];        // 16 KB
    __shared__ float sz[NN];        // 16 KB   -> total 48 KB, 2 blocks/CU

    const int tid  = threadIdx.x;
    const int lane = tid & 63;
    const int wv   = tid >> 6;
    const int bpb  = NN / QPB;
    const int batch    = blockIdx.x / bpb;
    const int nodeBase = (blockIdx.x % bpb) * QPB;

    const float* cb = coords + (size_t)batch * NN * 3;

    // ---- staging: contiguous writes across lanes -> conflict-free ----
    for (int p = tid; p < NN; p += BLOCK) {
        sx[p] = cb[3*p];
        sy[p] = cb[3*p+1];
        sz[p] = cb[3*p+2];
    }
    __syncthreads();

    const int q0 = nodeBase + wv * QPW;          // this wave's 4 query nodes
    const float x0 = sx[q0],   y0 = sy[q0],   z0 = sz[q0];
    const float x1 = sx[q0+1], y1 = sy[q0+1], z1 = sz[q0+1];
    const float x2 = sx[q0+2], y2 = sy[q0+2], z2 = sz[q0+2];
    const float x3 = sx[q0+3], y3 = sy[q0+3], z3 = sz[q0+3];

    const f32x2 qAx = {x0, x1}, qAy = {y0, y1}, qAz = {z0, z1};
    const f32x2 qBx = {x2, x3}, qBy = {y2, y3}, qBz = {z2, z3};

    // ---- phase 1: diagonal scan, packed top-2 ladders (2 FP ops each) ----
    float b0 = NEGB, s0 = NEGB, b1 = NEGB, s1 = NEGB;
    float b2 = NEGB, s2 = NEGB, b3 = NEGB, s3 = NEGB;

    #pragma unroll 8
    for (int c = 0; c < NN / 64; ++c) {
        int j = (c << 6) | (lane ^ c);
        float Px = sx[j], Py = sy[j], Pz = sz[j];
        float Pw = neg_half_n2(Px, Py, Pz);
        f32x2 vx = {Px, Px}, vy = {Py, Py}, vz = {Pz, Pz}, vw = {Pw, Pw};
        f32x2 dA = __builtin_elementwise_fma(vx, qAx,
                   __builtin_elementwise_fma(vy, qAy,
                   __builtin_elementwise_fma(vz, qAz, vw)));
        f32x2 dB = __builtin_elementwise_fma(vx, qBx,
                   __builtin_elementwise_fma(vy, qBy,
                   __builtin_elementwise_fma(vz, qBz, vw)));
        float d0 = __int_as_float((__float_as_int(dA.x) & PACKM) | c);
        float d1 = __int_as_float((__float_as_int(dA.y) & PACKM) | c);
        float d2 = __int_as_float((__float_as_int(dB.x) & PACKM) | c);
        float d3 = __int_as_float((__float_as_int(dB.y) & PACKM) | c);
        LADDER(d0, b0, s0)
        LADDER(d1, b1, s1)
        LADDER(d2, b2, s2)
        LADDER(d3, b3, s3)
    }

    SELFFIX(0, b0, s0)
    SELFFIX(1, b1, s1)
    SELFFIX(2, b2, s2)
    SELFFIX(3, b3, s3)

    // ---- redistribute: query q -> lanes 16q..16q+15; lane t owns columns
    //      {t, t+16, t+32, t+48} as slots 0..3 (column implicit)
    const int q  = lane >> 4;
    const int gt = lane & 15;
    float pb0, pb1, pb2, pb3, ps0, ps1, ps2, ps3;
    {
        const int ab = gt << 2;     // byte addr of source lane (column id)
#define PULL(K, PB, PS)                                                      \
        {   int a = ab + ((K) << 6);                                         \
            PB = sel4f(bpermf(a,b0), bpermf(a,b1), bpermf(a,b2), bpermf(a,b3), q); \
            PS = sel4f(bpermf(a,s0), bpermf(a,s1), bpermf(a,s2), bpermf(a,s3), q); \
        }
        PULL(0, pb0, ps0)
        PULL(1, pb1, ps1)
        PULL(2, pb2, ps2)
        PULL(3, pb3, ps3)
#undef PULL
    }

    // ---- phase 2: 16 rounds; 4 groups extract concurrently, no indices ----
    int selIdx = -1;                 // lane 16q + r holds edge r of query q

    #pragma unroll 1
    for (int r = 0; r < KNEI; ++r) {
        float f = fmaxf(fmaxf(pb0, pb1), fmaxf(pb2, pb3));
        int k = (f == pb3) ? 3 : ((f == pb2) ? 2 : ((f == pb1) ? 1 : 0));
        int cw = __float_as_int(f) & 63;
        int col = gt + (k << 4);
        int jl = (cw << 6) | (col ^ cw);
        int i = (k << 12) | jl;
        row_amax(f, i);             // every lane of the group now has (f,i)

        int j  = i & 4095;
        int kw = i >> 12;
        int colw = (j & 63) ^ (j >> 6);
        bool own = (gt == (colw & 15));

        if (gt == r) selIdx = j;

        bool exh = false;
        PROMOTE(0, pb0, ps0)
        PROMOTE(1, pb1, ps1)
        PROMOTE(2, pb2, ps2)
        PROMOTE(3, pb3, ps3)

        unsigned long long ex = __ballot(exh);
        if (ex) {                                 // rare refill path
            if ((ex >>  0) & 0xFFFFull) REPLAY(0, x0, y0, z0)
            if ((ex >> 16) & 0xFFFFull) REPLAY(1, x1, y1, z1)
            if ((ex >> 32) & 0xFFFFull) REPLAY(2, x2, y2, z2)
            if ((ex >> 48) & 0xFFFFull) REPLAY(3, x3, y3, z3)
        }
    }

    // ---- epilogue: each lane computes its edge's 24 S-components once ----
    float xq = (q & 2) ? ((q & 1) ? x3 : x2) : ((q & 1) ? x1 : x0);
    float yq = (q & 2) ? ((q & 1) ? y3 : y2) : ((q & 1) ? y1 : y0);
    float zq = (q & 2) ? ((q & 1) ? z3 : z2) : ((q & 1) ? z1 : z0);

    float px = sx[selIdx], py = sy[selIdx], pz = sz[selIdx];
    float rx = px - xq, ry = py - yq, rz = pz - zq;      // sender - receiver
    float dist = sqrtf(rx*rx + ry*ry + rz*rz);
    float inv  = 1.0f / (dist + 1e-8f);
    float hx = rx * inv, hy = ry * inv, hz = rz * inv;
    float cu = fminf(dist / 10.0f, 1.0f);
    float gg[8], ssum = 0.0f;
    #pragma unroll
    for (int v = 0; v < 8; ++v) {
        float d = cu - (float)v * (1.0f / 7.0f);
        gg[v] = expf(d * d * -32.0f);
        ssum += gg[v];
    }
    float is = 1.0f / ssum;
    float S[24];
    #pragma unroll
    for (int v = 0; v < 8; ++v) {
        float rbv = gg[v] * is;
        S[3*v]   = rbv * hx;
        S[3*v+1] = rbv * hy;
        S[3*v+2] = rbv * hz;
    }
    #pragma unroll
    for (int t = 0; t < 24; ++t) S[t] = row16_sum_dpp(S[t]);

    // W column straight from global (L2-hit; replaces the old sW LDS array)
    float wcol[8];
    #pragma unroll
    for (int v = 0; v < 8; ++v) wcol[v] = tpw[32*v + (lane & 31)];

    const float scale = 0.036084391824351613f;   // 1/(16*sqrt(3))
    const float4 z4 = make_float4(0.f, 0.f, 0.f, 0.f);

    #pragma unroll
    for (int qq = 0; qq < QPW; ++qq) {
        const int gq = batch * NN + q0 + qq;
        float sg[24];
        #pragma unroll
        for (int t = 0; t < 24; ++t) sg[t] = rlanef(S[t], 16 * qq + 15);

        float* onode = out + (size_t)gq * 464;
        float4* o4 = (float4*)onode;
        if (lane < 16)       o4[lane] = z4;          // ch 0..63
        else if (lane < 36)  o4[lane + 24] = z4;     // ch 160..239

        if (lane < 32) {
            float a0 = 0.f, a1 = 0.f, a2 = 0.f;
            #pragma unroll
            for (int v = 0; v < 8; ++v) {
                a0 = fmaf(wcol[v], sg[3*v],   a0);
                a1 = fmaf(wcol[v], sg[3*v+1], a1);
                a2 = fmaf(wcol[v], sg[3*v+2], a2);
            }
            onode[64 + 3*lane]     = a0 * scale;
            onode[64 + 3*lane + 1] = a1 * scale;
            onode[64 + 3*lane + 2] = a2 * scale;
        }

        const int at = atypes[gq];
        const int rt = rtypes[gq];
        if (lane < 56) {
            float4 v = (lane < 28)
                ? ((const float4*)(aemb + 112*at))[lane]
                : ((const float4*)(remb + 112*rt))[lane - 28];
            o4[60 + lane] = v;
        }
    }
}

extern "C" void kernel_launch(void* const* d_in, const int* in_sizes, int n_in,
                              void* d_out, int out_size, void* d_ws, size_t ws_size,
                              hipStream_t stream)
{
    const float* coords = (const float*)d_in[0];
    const int*   at     = (const int*)  d_in[1];
    const int*   rt     = (const int*)  d_in[2];
    const float* tpw    = (const float*)d_in[3];
    const float* ae     = (const float*)d_in[4];
    const float* re     = (const float*)d_in[5];
    float* out = (float*)d_out;

    const int B = in_sizes[1] / NN;                  // 8
    dim3 grid(B * (NN / QPB));
    protein_enc_kernel<<<grid, BLOCK, 0, stream>>>(coords, at, rt, tpw, ae, re, out);
}

// Round 14
// 73.712 us; speedup vs baseline: 1.0403x; 1.0403x over previous
//
#include <hip/hip_runtime.h>
#include <hip/hip_bf16.h>

#define NN    4096
#define KNEI  16
#define QPW   4              // query nodes per wave
#define WPB   16             // waves per block
#define BLOCK (WPB * 64)
#define QPB   (WPB * QPW)    // 64 queries per block
#define NEGB  -3.0e38f
#define PACKM 0xFFFFFFC0

typedef float f32x2 __attribute__((ext_vector_type(2)));
typedef int   i32x2 __attribute__((ext_vector_type(2)));

__device__ __forceinline__ int rlane(int v, int l)
{ return __builtin_amdgcn_readlane(v, l); }
__device__ __forceinline__ float rlanef(float v, int l)
{ return __int_as_float(__builtin_amdgcn_readlane(__float_as_int(v), l)); }

// f-only DPP max step (row_ror rotate-reduce)
template<int CTRL>
__device__ __forceinline__ float rmax_step(float f)
{
    int s_ = __builtin_amdgcn_update_dpp(__float_as_int(f), __float_as_int(f),
                                         CTRL, 0xF, 0xF, false);
    return fmaxf(f, __int_as_float(s_));
}

// (f,i) joint argmax step — replay path only
template<int CTRL>
__device__ __forceinline__ void amax_step(float& f, int& i)
{
    int fs = __builtin_amdgcn_update_dpp(__float_as_int(f), __float_as_int(f),
                                         CTRL, 0xF, 0xF, false);
    int is = __builtin_amdgcn_update_dpp(i, i, CTRL, 0xF, 0xF, false);
    float ff = __int_as_float(fs);
    bool gt = ff > f;
    f = gt ? ff : f;
    i = gt ? is : i;
}

__device__ __forceinline__ void wave_amax(float f, int i, float& M, int& mi)
{
    amax_step<0x111>(f, i); amax_step<0x112>(f, i); amax_step<0x114>(f, i);
    amax_step<0x118>(f, i); amax_step<0x142>(f, i); amax_step<0x143>(f, i);
    M  = rlanef(f, 63);
    mi = rlane(i, 63);
}

__device__ __forceinline__ float row16_sum_dpp(float v)  // lane 16r+15 -> row sum
{
    float f = v;
#define STEPA(CTRL)                                                          \
    { int s_ = __builtin_amdgcn_update_dpp(0, __float_as_int(f),             \
               (CTRL), 0xF, 0xF, true);                                      \
      f += __int_as_float(s_); }
    STEPA(0x111) STEPA(0x112) STEPA(0x114) STEPA(0x118)
#undef STEPA
    return f;
}

__device__ __forceinline__ float bpermf(int abyte, float v)
{ return __int_as_float(__builtin_amdgcn_ds_bpermute(abyte, __float_as_int(v))); }

__device__ __forceinline__ float sel4f(float a, float b, float c, float d, int q)
{
    float lo = (q & 1) ? b : a;
    float hi = (q & 1) ? d : c;
    return (q & 2) ? hi : lo;
}

// purge self (always its column's packed max, possibly packed 2nd)
#define SELFFIX(q, b, s)                                                     \
    {  int cb_ = __float_as_int(b) & 63;                                     \
       if ((((cb_) << 6) | (lane ^ cb_)) == q0 + (q)) { (b) = (s); (s) = NEGB; } \
       int cs_ = __float_as_int(s) & 63;                                     \
       if ((((cs_) << 6) | (lane ^ cs_)) == q0 + (q)) { (s) = NEGB; } }

// rare wave-wide replay: rebuild column colq's top-2 unselected members
#define REPLAY(qq, xq, yq, zq)                                               \
    {   int wq = __ffsll(ex & (0xFFFFull << ((qq) * 16))) - 1;               \
        int colq = rlane(col, wq);                                           \
        int kq   = rlane(kf,  wq);                                           \
        int j2 = (lane << 6) | (colq ^ lane);                                \
        float4 Pp = pts[j2];                                                 \
        float scr = fmaf(Pp.x,(xq), fmaf(Pp.y,(yq), fmaf(Pp.z,(zq), Pp.w))); \
        float sf = __int_as_float((__float_as_int(scr) & PACKM) | lane);     \
        if (j2 == q0 + (qq)) sf = NEGB;                                      \
        const int4* sp = (const int4*)&sel[wv * 64 + ((qq) << 4)];           \
        int4 sa = sp[0], sb = sp[1], sc = sp[2], sd = sp[3];                 \
        if (j2==sa.x || j2==sa.y || j2==sa.z || j2==sa.w) sf = NEGB;         \
        if (j2==sb.x || j2==sb.y || j2==sb.z || j2==sb.w) sf = NEGB;         \
        if (j2==sc.x || j2==sc.y || j2==sc.z || j2==sc.w) sf = NEGB;         \
        if (j2==sd.x || j2==sd.y || j2==sd.z || j2==sd.w) sf = NEGB;         \
        float M1; int i1;                                                    \
        wave_amax(sf, j2, M1, i1);                                           \
        float sf2 = (j2 == i1) ? NEGB : sf;                                  \
        float M2; int i2;                                                    \
        wave_amax(sf2, j2, M2, i2);                                          \
        bool ow = (lane == (qq) * 16 + (colq & 15));                         \
        if (kq == 0)      { pb0 = ow ? M1 : pb0; ps0 = ow ? M2 : ps0; }      \
        else if (kq == 1) { pb1 = ow ? M1 : pb1; ps1 = ow ? M2 : ps1; }      \
        else if (kq == 2) { pb2 = ow ? M1 : pb2; ps2 = ow ? M2 : ps2; }      \
        else              { pb3 = ow ? M1 : pb3; ps3 = ow ? M2 : ps3; }      \
    }

__global__ __launch_bounds__(BLOCK, 8)
void protein_enc_kernel(const float* __restrict__ coords,
                        const int*   __restrict__ atypes,
                        const int*   __restrict__ rtypes,
                        const float* __restrict__ tpw,
                        const float* __restrict__ aemb,
                        const float* __restrict__ remb,
                        float* __restrict__ out)
{
    __shared__ float4 pts[NN];          // 64 KB: x, y, z, -n2/2
    __shared__ float  sW[8 * 32];
    __shared__ int    sel[WPB * 64];    // 4 KB: [wave][q][r] selected indices

    const int tid  = threadIdx.x;
    const int lane = tid & 63;
    const int wv   = tid >> 6;
    const int bpb  = NN / QPB;
    const int batch    = blockIdx.x / bpb;
    const int nodeBase = (blockIdx.x % bpb) * QPB;

    const float* cb = coords + (size_t)batch * NN * 3;

    // ---- staging: contiguous float4 writes (R12 pattern, conflict-free) ----
    for (int p = tid; p < NN; p += BLOCK) {
        float x = cb[3*p], y = cb[3*p+1], z = cb[3*p+2];
        pts[p] = make_float4(x, y, z, -0.5f * (x*x + y*y + z*z));
    }
    if (tid < 256) sW[tid] = tpw[tid];
    sel[wv * 64 + lane] = -1;           // wave-private init, no barrier needed
    __syncthreads();

    const int q0 = nodeBase + wv * QPW;          // this wave's 4 query nodes
    const float4 P0 = pts[q0],   P1 = pts[q0+1];
    const float4 P2 = pts[q0+2], P3 = pts[q0+3];
    const float x0 = P0.x, y0 = P0.y, z0 = P0.z;
    const float x1 = P1.x, y1 = P1.y, z1 = P1.z;
    const float x2 = P2.x, y2 = P2.y, z2 = P2.z;
    const float x3 = P3.x, y3 = P3.y, z3 = P3.z;

    const f32x2 qAx = {x0, x1}, qAy = {y0, y1}, qAz = {z0, z1};
    const f32x2 qBx = {x2, x3}, qBy = {y2, y3}, qBz = {z2, z3};
    const i32x2 M2v = {(int)PACKM, (int)PACKM};

    // ---- phase 1: diagonal scan; packed top-2 ladders in pk (VOP3P) ops ----
    f32x2 bA = {NEGB, NEGB}, sA = {NEGB, NEGB};
    f32x2 bB = {NEGB, NEGB}, sB = {NEGB, NEGB};

    #pragma unroll 8
    for (int c = 0; c < NN / 64; ++c) {
        int j = (c << 6) | (lane ^ c);
        float4 P = pts[j];
        f32x2 vx = {P.x, P.x}, vy = {P.y, P.y}, vz = {P.z, P.z}, vw = {P.w, P.w};
        f32x2 dA = __builtin_elementwise_fma(vx, qAx,
                   __builtin_elementwise_fma(vy, qAy,
                   __builtin_elementwise_fma(vz, qAz, vw)));
        f32x2 dB = __builtin_elementwise_fma(vx, qBx,
                   __builtin_elementwise_fma(vy, qBy,
                   __builtin_elementwise_fma(vz, qBz, vw)));
        i32x2 cc = {c, c};
        f32x2 pA = __builtin_bit_cast(f32x2,
                     (__builtin_bit_cast(i32x2, dA) & M2v) | cc);
        f32x2 pB = __builtin_bit_cast(f32x2,
                     (__builtin_bit_cast(i32x2, dB) & M2v) | cc);
        // s = max(s, min(p, b_old)); b = max(b, p)   (== med3 ladder)
        sA = __builtin_elementwise_max(sA, __builtin_elementwise_min(pA, bA));
        bA = __builtin_elementwise_max(bA, pA);
        sB = __builtin_elementwise_max(sB, __builtin_elementwise_min(pB, bB));
        bB = __builtin_elementwise_max(bB, pB);
    }

    float b0 = bA.x, b1 = bA.y, b2 = bB.x, b3 = bB.y;
    float s0 = sA.x, s1 = sA.y, s2 = sB.x, s3 = sB.y;

    SELFFIX(0, b0, s0)
    SELFFIX(1, b1, s1)
    SELFFIX(2, b2, s2)
    SELFFIX(3, b3, s3)

    // ---- redistribute: query q -> lanes 16q..16q+15; lane t owns columns
    //      {t, t+16, t+32, t+48} as slots 0..3 ----
    const int q  = lane >> 4;
    const int gt = lane & 15;
    float pb0, pb1, pb2, pb3, ps0, ps1, ps2, ps3;
    {
        const int ab = gt << 2;     // byte addr of source lane (column id)
#define PULL(K, PB, PS)                                                      \
        {   int a = ab + ((K) << 6);                                         \
            PB = sel4f(bpermf(a,b0), bpermf(a,b1), bpermf(a,b2), bpermf(a,b3), q); \
            PS = sel4f(bpermf(a,s0), bpermf(a,s1), bpermf(a,s2), bpermf(a,s3), q); \
        }
        PULL(0, pb0, ps0)
        PULL(1, pb1, ps1)
        PULL(2, pb2, ps2)
        PULL(3, pb3, ps3)
#undef PULL
    }

    // ---- phase 2: 16 rounds; f-only row reduce + owner-claim ----
    const unsigned long long gmask = 0xFFFFull << (q << 4);
    const int selbase = wv * 64 + (q << 4);

    #pragma unroll 1
    for (int r = 0; r < KNEI; ++r) {
        float f = fmaxf(fmaxf(pb0, pb1), fmaxf(pb2, pb3));
        f = rmax_step<0x121>(f); f = rmax_step<0x122>(f);
        f = rmax_step<0x124>(f); f = rmax_step<0x128>(f);
        // owner claim: bit-exact match against the row max
        bool c0 = (pb0 == f), c1 = (pb1 == f), c2 = (pb2 == f), c3 = (pb3 == f);
        unsigned long long m = __ballot(c0 | c1 | c2 | c3);
        int w = __ffsll(m & gmask) - 1;
        bool iwin = (lane == w);
        int kf = c0 ? 0 : (c1 ? 1 : (c2 ? 2 : 3));       // priority slot
        bool o0 = iwin && c0;
        bool o1 = iwin && !c0 && c1;
        bool o2 = iwin && !c0 && !c1 && c2;
        bool o3 = iwin && !c0 && !c1 && !c2;
        int cw  = __float_as_int(f) & 63;                // winner's row
        int col = gt + (kf << 4);                        // valid at owner
        int jw  = (cw << 6) | (col ^ cw);
        if (iwin) sel[selbase + r] = jw;
        float pskf = o1 ? ps1 : (o2 ? ps2 : (o3 ? ps3 : ps0));
        bool e = iwin && (pskf == NEGB);
        pb0 = o0 ? ps0 : pb0;  ps0 = o0 ? NEGB : ps0;
        pb1 = o1 ? ps1 : pb1;  ps1 = o1 ? NEGB : ps1;
        pb2 = o2 ? ps2 : pb2;  ps2 = o2 ? NEGB : ps2;
        pb3 = o3 ? ps3 : pb3;  ps3 = o3 ? NEGB : ps3;
        unsigned long long ex = __ballot(e);
        if (ex) {                                 // rare refill path
            if ((ex >>  0) & 0xFFFFull) REPLAY(0, x0, y0, z0)
            if ((ex >> 16) & 0xFFFFull) REPLAY(1, x1, y1, z1)
            if ((ex >> 32) & 0xFFFFull) REPLAY(2, x2, y2, z2)
            if ((ex >> 48) & 0xFFFFull) REPLAY(3, x3, y3, z3)
        }
    }

    // ---- epilogue: lane (16q+gt) owns edge gt of query q ----
    int selIdx = sel[wv * 64 + lane];

    float xq = (q & 2) ? ((q & 1) ? x3 : x2) : ((q & 1) ? x1 : x0);
    float yq = (q & 2) ? ((q & 1) ? y3 : y2) : ((q & 1) ? y1 : y0);
    float zq = (q & 2) ? ((q & 1) ? z3 : z2) : ((q & 1) ? z1 : z0);

    float4 P = pts[selIdx];
    float rx = P.x - xq, ry = P.y - yq, rz = P.z - zq;   // sender - receiver
    float dist = sqrtf(rx*rx + ry*ry + rz*rz);
    float inv  = 1.0f / (dist + 1e-8f);
    float hx = rx * inv, hy = ry * inv, hz = rz * inv;
    float cu = fminf(dist / 10.0f, 1.0f);
    // g[v] = exp(-32(cu - v/7)^2) = A * E^v * K[v];  2 expf instead of 8
    float A = expf(cu * cu * -32.0f);
    float E = expf(cu * (64.0f / 7.0f));
    const float K[8] = {1.0f, 0.5204501f, 0.0733697f, 0.00280164f,
                        2.897772e-05f, 8.11857e-08f, 6.16130e-11f,
                        1.2664166e-14f};
    float gg[8];
    float t = A, ssum = A;
    gg[0] = A;
    #pragma unroll
    for (int v = 1; v < 8; ++v) { t *= E; gg[v] = t * K[v]; ssum += gg[v]; }
    float is = 1.0f / ssum;
    float S[24];
    #pragma unroll
    for (int v = 0; v < 8; ++v) {
        float rbv = gg[v] * is;
        S[3*v]   = rbv * hx;
        S[3*v+1] = rbv * hy;
        S[3*v+2] = rbv * hz;
    }
    #pragma unroll
    for (int t2 = 0; t2 < 24; ++t2) S[t2] = row16_sum_dpp(S[t2]);

    float wcol[8];
    #pragma unroll
    for (int v = 0; v < 8; ++v) wcol[v] = sW[32*v + (lane & 31)];

    const float scale = 0.036084391824351613f;   // 1/(16*sqrt(3))
    const float4 z4 = make_float4(0.f, 0.f, 0.f, 0.f);

    #pragma unroll
    for (int qq = 0; qq < QPW; ++qq) {
        const int gq = batch * NN + q0 + qq;
        float sg[24];
        #pragma unroll
        for (int t2 = 0; t2 < 24; ++t2) sg[t2] = rlanef(S[t2], 16 * qq + 15);

        float* onode = out + (size_t)gq * 464;
        float4* o4 = (float4*)onode;
        if (lane < 16)       o4[lane] = z4;          // ch 0..63
        else if (lane < 36)  o4[lane + 24] = z4;     // ch 160..239

        if (lane < 32) {
            float a0 = 0.f, a1 = 0.f, a2 = 0.f;
            #pragma unroll
            for (int v = 0; v < 8; ++v) {
                a0 = fmaf(wcol[v], sg[3*v],   a0);
                a1 = fmaf(wcol[v], sg[3*v+1], a1);
                a2 = fmaf(wcol[v], sg[3*v+2], a2);
            }
            onode[64 + 3*lane]     = a0 * scale;
            onode[64 + 3*lane + 1] = a1 * scale;
            onode[64 + 3*lane + 2] = a2 * scale;
        }

        const int at = atypes[gq];
        const int rt = rtypes[gq];
        if (lane < 56) {
            float4 v = (lane < 28)
                ? ((const float4*)(aemb + 112*at))[lane]
                : ((const float4*)(remb + 112*rt))[lane - 28];
            o4[60 + lane] = v;
        }
    }
}

extern "C" void kernel_launch(void* const* d_in, const int* in_sizes, int n_in,
                              void* d_out, int out_size, void* d_ws, size_t ws_size,
                              hipStream_t stream)
{
    const float* coords = (const float*)d_in[0];
    const int*   at     = (const int*)  d_in[1];
    const int*   rt     = (const int*)  d_in[2];
    const float* tpw    = (const float*)d_in[3];
    const float* ae     = (const float*)d_in[4];
    const float* re     = (const float*)d_in[5];
    float* out = (float*)d_out;

    const int B = in_sizes[1] / NN;                  // 8
    dim3 grid(B * (NN / QPB));
    protein_enc_kernel<<<grid, BLOCK, 0, stream>>>(coords, at, rt, tpw, ae, re, out);
}